// Round 10
// baseline (667.265 us; speedup 1.0000x reference)
//
#include <hip/hip_runtime.h>
#include <hip/hip_bf16.h>
#include <math.h>

#define NN 16
#define CC 64
#define TT_ 634
#define VV 26
#define TV 16484      // TT_*VV
#define KK 3
#define OO 192        // KK*CC
#define TKK 9
#define NCLS 60
#define NAE 4
#define EPS 1e-5f

typedef __attribute__((ext_vector_type(8))) short short8;
typedef __attribute__((ext_vector_type(4))) float f32x4;

static __device__ __forceinline__ float bf2f(unsigned int u) {
  union { unsigned int i; float f; } v; v.i = u << 16; return v.f;
}
static __device__ __forceinline__ unsigned int f2bf(float x) {
  union { float f; unsigned int i; } v; v.f = x;
  unsigned int r = v.i + 0x7fffu + ((v.i >> 16) & 1u);
  return r >> 16;
}

#define W1_ELEMS (3 * OO * CC)     // 36864
#define W2_ELEMS (3 * CC * 576)    // 110592
#define AM_ELEMS (3 * KK * 1024)   // 9216

// ---------------------------------------------------------------------------
// Prep (once): all 3 layers' weights -> bf16.  (validated R6)
// ---------------------------------------------------------------------------
__global__ __launch_bounds__(256) void k_prep_all(
    const float* __restrict__ sgc_w, const float* __restrict__ tconv_w,
    const float* __restrict__ Ap, const float* __restrict__ Mp,
    unsigned short* __restrict__ W1all, unsigned short* __restrict__ W2all,
    unsigned short* __restrict__ AMall)
{
  int j = blockIdx.x * 256 + threadIdx.x;
  if (j < W1_ELEMS) { W1all[j] = (unsigned short)f2bf(sgc_w[j]); return; }
  j -= W1_ELEMS;
  if (j < W2_ELEMS) {
    const int i = j / (CC * 576), r = j % (CC * 576);
    const int c = r / 576, q = r % 576, dt = q >> 6, ci = q & 63;
    W2all[j] = (unsigned short)f2bf(
        tconv_w[(size_t)i * CC * CC * TKK + c * 576 + ci * 9 + dt]);
    return;
  }
  j -= W2_ELEMS;
  if (j < AM_ELEMS) {
    const int i = j / (KK * 1024), r = j % (KK * 1024);
    const int k = r >> 10, rr = r & 1023;
    const int w = rr >> 5, v = rr & 31;
    float val = 0.f;
    if (w < VV && v < VV)
      val = Ap[(k * VV + v) * VV + w] *
            Mp[((size_t)i * KK + k) * VV * VV + v * VV + w];
    AMall[j] = (unsigned short)f2bf(val);
  }
}

// ---------------------------------------------------------------------------
// Fused SGC (R9: 512 threads / 8 waves for occupancy).
// GEMM1: M=192 o, N=128 f (112 live + 16 zero-pad), K=64. Waves 4m x 2n:
//        wave tile 48o x 64f (acc[3][4]).  sH [128 f][64 ci] overlaid in sY.
// GEMM2: 2 waves per t (c-halves of 32): acc[2][2]. AM frags loaded late.
// sY store guard col<112 (pitch 120).
// ---------------------------------------------------------------------------
template<int F32IN>
__global__ __launch_bounds__(512) void k_fused_sgc(
    const void* __restrict__ hin,           // [16][64][TV] f32 or bf16
    const unsigned short* __restrict__ W1,  // [192][64] bf16 layer slice
    const float* __restrict__ Wb,           // [192]
    const unsigned short* __restrict__ AMk, // [KK][32][32] bf16 layer slice
    const float* __restrict__ bg, const float* __restrict__ bb,
    const float* __restrict__ bm, const float* __restrict__ bv,
    unsigned short* __restrict__ hout)      // [16][64][TV] bf16
{
  const int NTT = 159;
  const int n = blockIdx.x / NTT, tt = blockIdx.x % NTT;
  const int t0 = tt << 2;
  const int f0 = t0 * VV;
  const int tid = threadIdx.x;
  const int wv = tid >> 6, lane = tid & 63;
  const int l15 = lane & 15, l4 = lane >> 4;

  __shared__ unsigned short sY[192 * 120];  // 46080 B; sH aliased on top
  __shared__ float sWb[OO];
  __shared__ float sS[CC], sOff[CC];
  unsigned short* sH = sY;                  // [f 128][ci 64] during GEMM1

  // GEMM1 A-frags (W1, 24 KB L2): wave = (mq, nh)
  const int mq = wv >> 1;            // 0..3 -> m0 = mq*48
  const int nh = wv & 1;             // 0..1 -> n0 = nh*64
  const int m0 = mq * 48, n0 = nh << 6;
  short8 afr[2][3];
  #pragma unroll
  for (int ks = 0; ks < 2; ++ks)
    #pragma unroll
    for (int mf = 0; mf < 3; ++mf)
      afr[ks][mf] = *(const short8*)(W1 + (size_t)(m0 + mf * 16 + l15) * CC
                                     + (ks << 5) + (l4 << 3));

  if (tid < OO) {
    sWb[tid] = Wb[tid];
  } else if (tid >= 192 && tid < 256) {
    const int c = tid - 192;
    const float s = bg[c] * rsqrtf(bv[c] + EPS);
    sS[c] = s;
    sOff[c] = bb[c] - bm[c] * s;
  }

  // ---- stage sH: [f 0..127][ci 64], f>=104 zeroed, XOR-swizzled ----
  for (int it = tid; it < 16 * 64; it += 512) {
    const int ci = it & 63, fc = it >> 6;   // fc 0..15
    const int flb = fc << 3;
    const int fg = f0 + flb;
    unsigned short e[8];
    if (flb >= 104) {
      #pragma unroll
      for (int j = 0; j < 8; ++j) e[j] = 0;
    } else if (F32IN) {
      const float* hb = (const float*)hin + ((size_t)n * CC + ci) * TV;
      if (fg + 8 <= TV) {
        const float4 v0 = *(const float4*)(hb + fg);
        const float4 v1 = *(const float4*)(hb + fg + 4);
        e[0] = (unsigned short)f2bf(v0.x); e[1] = (unsigned short)f2bf(v0.y);
        e[2] = (unsigned short)f2bf(v0.z); e[3] = (unsigned short)f2bf(v0.w);
        e[4] = (unsigned short)f2bf(v1.x); e[5] = (unsigned short)f2bf(v1.y);
        e[6] = (unsigned short)f2bf(v1.z); e[7] = (unsigned short)f2bf(v1.w);
      } else {
        #pragma unroll
        for (int j = 0; j < 8; ++j)
          e[j] = (fg + j < TV) ? (unsigned short)f2bf(hb[fg + j])
                               : (unsigned short)0;
      }
    } else {
      const unsigned short* hb = (const unsigned short*)hin
                                 + ((size_t)n * CC + ci) * TV;
      if (fg + 8 <= TV) {
        const uint2 v0 = *(const uint2*)(hb + fg);
        const uint2 v1 = *(const uint2*)(hb + fg + 4);
        e[0] = (unsigned short)(v0.x & 0xffffu); e[1] = (unsigned short)(v0.x >> 16);
        e[2] = (unsigned short)(v0.y & 0xffffu); e[3] = (unsigned short)(v0.y >> 16);
        e[4] = (unsigned short)(v1.x & 0xffffu); e[5] = (unsigned short)(v1.x >> 16);
        e[6] = (unsigned short)(v1.y & 0xffffu); e[7] = (unsigned short)(v1.y >> 16);
      } else {
        #pragma unroll
        for (int j = 0; j < 8; ++j)
          e[j] = (fg + j < TV) ? hb[fg + j] : (unsigned short)0;
      }
    }
    const int cg8 = ci >> 3, cl = ci & 7;
    #pragma unroll
    for (int j = 0; j < 8; ++j)     // flb%8==0 -> ((flb+j)&7)==j
      sH[((flb + j) << 6) + ((cg8 ^ j) << 3) + cl] = e[j];
  }
  __syncthreads();

  // ---- GEMM1: 48 o x 64 f per wave (reads sH; acc stays in regs) ----
  f32x4 acc[3][4] = {};
  #pragma unroll
  for (int ks = 0; ks < 2; ++ks) {
    short8 bfr[4];
    const int cg = (ks << 2) + l4;
    #pragma unroll
    for (int nf = 0; nf < 4; ++nf) {
      const int fl = n0 + (nf << 4) + l15;
      bfr[nf] = *(const short8*)&sH[(fl << 6) + ((cg ^ (fl & 7)) << 3)];
    }
    #pragma unroll
    for (int mf = 0; mf < 3; ++mf)
      #pragma unroll
      for (int nf = 0; nf < 4; ++nf)
        acc[mf][nf] = __builtin_amdgcn_mfma_f32_16x16x32_bf16(
            afr[ks][mf], bfr[nf], acc[mf][nf], 0, 0, 0);
  }
  __syncthreads();   // sH reads done -> safe to overwrite with sY

  // epilogue -> sY (only cols < 112 stored; pad cols discarded)
  #pragma unroll
  for (int mf = 0; mf < 3; ++mf)
    #pragma unroll
    for (int r = 0; r < 4; ++r) {
      const int o = m0 + mf * 16 + (l4 << 2) + r;
      const float bias = sWb[o];
      #pragma unroll
      for (int nf = 0; nf < 4; ++nf) {
        const int col = n0 + (nf << 4) + l15;
        if (col < 112)
          sY[o * 120 + col] = (unsigned short)f2bf(acc[mf][nf][r] + bias);
      }
    }
  __syncthreads();

  // ---- GEMM2: 2 waves per t (c-halves); M=32 c, N=2x16 w, K=3x32 ----
  const int tl = wv >> 1;            // 0..3
  const int ch = wv & 1;             // c-half
  const int t = t0 + tl;
  if (t < TT_) {
    short8 amf[KK][2];
    #pragma unroll
    for (int k = 0; k < KK; ++k)
      #pragma unroll
      for (int nf = 0; nf < 2; ++nf)
        amf[k][nf] = *(const short8*)(AMk + (k << 10) + ((nf * 16 + l15) << 5)
                                      + (l4 << 3));
    f32x4 a2[2][2] = {};
    const int cuoff = tl * 13 + (l4 << 2);   // uint offset in sY row
    #pragma unroll
    for (int k = 0; k < KK; ++k)
      #pragma unroll
      for (int mf = 0; mf < 2; ++mf) {
        const unsigned int* rb =
            (const unsigned int*)&sY[(k * 64 + (ch << 5) + mf * 16 + l15) * 120];
        union { unsigned int u[4]; short8 s; } av;
        av.u[0] = rb[cuoff];     av.u[1] = rb[cuoff + 1];
        av.u[2] = rb[cuoff + 2]; av.u[3] = rb[cuoff + 3];
        #pragma unroll
        for (int nf = 0; nf < 2; ++nf)
          a2[mf][nf] = __builtin_amdgcn_mfma_f32_16x16x32_bf16(
              av.s, amf[k][nf], a2[mf][nf], 0, 0, 0);
      }
    #pragma unroll
    for (int mf = 0; mf < 2; ++mf)
      #pragma unroll
      for (int r = 0; r < 4; ++r) {
        const int c = (ch << 5) + mf * 16 + (l4 << 2) + r;
        const float s = sS[c], off = sOff[c];
        unsigned short* op = hout + ((size_t)n * CC + c) * TV + t * VV;
        op[l15] = (unsigned short)f2bf(fmaxf(fmaf(a2[mf][0][r], s, off), 0.f));
        if (l15 < 10)
          op[16 + l15] =
              (unsigned short)f2bf(fmaxf(fmaf(a2[mf][1][r], s, off), 0.f));
      }
  }
}

// ---------------------------------------------------------------------------
// K2 (MFMA): temporal conv.  R9: 512 threads / 8 waves; wave tile 64c x 32f
// (acc[4][2]).  ci-split staging (2x32) unchanged; swapped operands
// (C row=f, col=c) unchanged.
// ---------------------------------------------------------------------------
template<int F32OUT>
__global__ __launch_bounds__(512) void k_tconv_mfma(
    const unsigned short* __restrict__ xin,  // [16][64][TV] bf16
    const unsigned short* __restrict__ W2,   // [64][576] bf16
    const float* __restrict__ wb, const float* __restrict__ bg,
    const float* __restrict__ bb, const float* __restrict__ bm,
    const float* __restrict__ bv, void* __restrict__ xout)
{
  const int NFT = (TV + 255) >> 8;  // 65
  const int n = blockIdx.x / NFT, ft = blockIdx.x % NFT;
  const int f0 = ft << 8;
  const int tid = threadIdx.x;
  const int w = tid >> 6, lane = tid & 63;
  const int l15 = lane & 15, l4 = lane >> 4;
  __shared__ unsigned short sIn[464 * 32];  // 29696 B, [f][ci32] swizzled

  const unsigned short* xb = xin + (size_t)n * CC * TV;
  const int wf0 = w << 5;            // wave f-offset (32 per wave)
  f32x4 acc[4][2] = {};   // [c-tile][f-tile], row=f col=c

  for (int cc = 0; cc < 2; ++cc) {
    if (cc) __syncthreads();
    // ---- stage 32-ci chunk ----
    for (int it = tid; it < 58 * 32; it += 512) {
      const int ci = it & 31, fc = it >> 5;   // fc 0..57
      const int flb = fc << 3;
      const int fg = f0 - 104 + flb;
      const int cig = (cc << 5) + ci;
      unsigned short e[8];
      if (fg >= 0 && fg + 8 <= TV) {
        const uint2 v0 = *(const uint2*)(xb + (size_t)cig * TV + fg);
        const uint2 v1 = *(const uint2*)(xb + (size_t)cig * TV + fg + 4);
        e[0] = (unsigned short)(v0.x & 0xffffu); e[1] = (unsigned short)(v0.x >> 16);
        e[2] = (unsigned short)(v0.y & 0xffffu); e[3] = (unsigned short)(v0.y >> 16);
        e[4] = (unsigned short)(v1.x & 0xffffu); e[5] = (unsigned short)(v1.x >> 16);
        e[6] = (unsigned short)(v1.y & 0xffffu); e[7] = (unsigned short)(v1.y >> 16);
      } else {
        #pragma unroll
        for (int j = 0; j < 8; ++j) {
          const int f = fg + j;
          e[j] = (f >= 0 && f < TV) ? xb[(size_t)cig * TV + f] : (unsigned short)0;
        }
      }
      const int cg8 = ci >> 3, cl = ci & 7;
      #pragma unroll
      for (int j = 0; j < 8; ++j) {
        const int fl = flb + j;
        sIn[(fl << 5) + ((cg8 ^ ((fl >> 1) & 3)) << 3) + cl] = e[j];
      }
    }
    __syncthreads();

    // ---- 9 dt k-steps (K=32 ci each) ----
    short8 wCur[4], wNxt[4];
    {
      const int koff = (cc << 5) + (l4 << 3);   // dt = 0
      #pragma unroll
      for (int mt = 0; mt < 4; ++mt)
        wCur[mt] = *(const short8*)(W2 + (size_t)(mt * 16 + l15) * 576 + koff);
    }
    for (int dt = 0; dt < TKK; ++dt) {
      if (dt < 8) {
        const int koff = ((dt + 1) << 6) + (cc << 5) + (l4 << 3);
        #pragma unroll
        for (int mt = 0; mt < 4; ++mt)
          wNxt[mt] = *(const short8*)(W2 + (size_t)(mt * 16 + l15) * 576 + koff);
      }
      const int flb = wf0 + l15 + (dt - 4) * 26 + 104;
      short8 ifr[2];
      #pragma unroll
      for (int nt = 0; nt < 2; ++nt) {
        const int fl = flb + (nt << 4);
        ifr[nt] = *(const short8*)&sIn[(fl << 5)
                                       + ((l4 ^ ((fl >> 1) & 3)) << 3)];
      }
      #pragma unroll
      for (int mt = 0; mt < 4; ++mt)
        #pragma unroll
        for (int nt = 0; nt < 2; ++nt)
          acc[mt][nt] = __builtin_amdgcn_mfma_f32_16x16x32_bf16(
              ifr[nt], wCur[mt], acc[mt][nt], 0, 0, 0);
      if (dt < 8) {
        #pragma unroll
        for (int mt = 0; mt < 4; ++mt) wCur[mt] = wNxt[mt];
      }
    }
  }

  // ---- epilogue: row=f=(l4<<2)+r, col=c=l15; 4 consecutive f per lane ----
  #pragma unroll
  for (int mt = 0; mt < 4; ++mt) {
    const int c = mt * 16 + l15;
    const float sc = bg[c] * rsqrtf(bv[c] + EPS);
    const float off = fmaf(wb[c] - bm[c], sc, bb[c]);
    #pragma unroll
    for (int nt = 0; nt < 2; ++nt) {
      const int fbase = f0 + wf0 + (nt << 4) + (l4 << 2);
      if (fbase < TV) {   // TV%4==0 -> quad fully in or out
        float v0 = fmaxf(fmaf(acc[mt][nt][0], sc, off), 0.f);
        float v1 = fmaxf(fmaf(acc[mt][nt][1], sc, off), 0.f);
        float v2 = fmaxf(fmaf(acc[mt][nt][2], sc, off), 0.f);
        float v3 = fmaxf(fmaf(acc[mt][nt][3], sc, off), 0.f);
        if (F32OUT) {
          float4 o4; o4.x = v0; o4.y = v1; o4.z = v2; o4.w = v3;
          *(float4*)((float*)xout + ((size_t)n * CC + c) * TV + fbase) = o4;
        } else {
          uint2 pk;
          pk.x = f2bf(v0) | (f2bf(v1) << 16);
          pk.y = f2bf(v2) | (f2bf(v3) << 16);
          *(uint2*)((unsigned short*)xout + ((size_t)n * CC + c) * TV + fbase) = pk;
        }
      }
    }
  }
}

// ---------------------------------------------------------------------------
// K3a: pooled / per-v T-mean  (unchanged, reads f32 bufB)
// ---------------------------------------------------------------------------
__global__ __launch_bounds__(256) void k_pool(
    const float* __restrict__ h, float* __restrict__ pooled,
    float* __restrict__ hmeanv)
{
  const int tid = threadIdx.x;
  const int bid = blockIdx.x;
  const float* row = h + (size_t)bid * TV;
  __shared__ float part[9 * VV];
  if (tid < 9 * VV) {
    const int tt = tid / VV, v = tid - tt * VV;
    float s = 0.f;
    for (int t = tt; t < TT_; t += 9) s += row[t * VV + v];
    part[tid] = s;
  }
  __syncthreads();
  if (tid < VV) {
    float tot = 0.f;
    #pragma unroll
    for (int j = 0; j < 9; ++j) tot += part[j * VV + tid];
    hmeanv[(size_t)bid * VV + tid] = tot / (float)TT_;
    part[tid] = tot;
  }
  __syncthreads();
  if (tid == 0) {
    float tot = 0.f;
    for (int v = 0; v < VV; ++v) tot += part[v];
    pooled[bid] = tot / (float)TV;
  }
}

// ---------------------------------------------------------------------------
// K3b: per-n head  (unchanged)
// ---------------------------------------------------------------------------
__global__ __launch_bounds__(256) void k_head_edge(
    const float* __restrict__ pooled, const float* __restrict__ hmeanv,
    const float* __restrict__ fcw, const float* __restrict__ fcb,
    const float* __restrict__ ag, const float* __restrict__ ab,
    const float* __restrict__ am, const float* __restrict__ av,
    const float* __restrict__ attw, const float* __restrict__ edgew,
    const float* __restrict__ eg, const float* __restrict__ eb,
    const float* __restrict__ em, const float* __restrict__ ev,
    float* __restrict__ dout)
{
  const int tid = threadIdx.x;
  const int n = blockIdx.x;
  __shared__ float sbnm[CC * VV];
  __shared__ float sxam[NCLS * VV];
  __shared__ float spool[CC];
  for (int i = tid; i < CC * VV; i += 256) {
    const int c = i / VV;
    const float s = ag[c] * rsqrtf(av[c] + EPS);
    const float off = ab[c] - am[c] * s;
    sbnm[i] = fmaf(hmeanv[(size_t)(n * CC) * VV + i], s, off);
  }
  if (tid < CC) spool[tid] = pooled[n * CC + tid];
  __syncthreads();
  for (int i = tid; i < NCLS * VV; i += 256) {
    const int o = i / VV, v = i - o * VV;
    float a = 0.f;
    for (int c = 0; c < CC; ++c) a = fmaf(attw[o * CC + c], sbnm[c * VV + v], a);
    sxam[i] = a;
  }
  if (tid < NCLS) {
    float a = fcb[tid];
    for (int c = 0; c < CC; ++c) a = fmaf(spool[c], fcw[tid * CC + c], a);
    dout[n * NCLS + tid] = a;
  }
  __syncthreads();
  for (int i = tid; i < NAE * VV * VV; i += 256) {
    const int j = i / VV, v = i - j * VV;
    float a = 0.f;
    for (int o = 0; o < NCLS; ++o) a = fmaf(edgew[j * NCLS + o], sxam[o * VV + v], a);
    const float s = eg[j] * rsqrtf(ev[j] + EPS);
    const float val = tanhf(fmaf(a - em[j], s, eb[j]));
    dout[NN * NCLS + (size_t)NN * TV + (size_t)n * NAE * VV * VV + i] = fmaxf(val, 0.f);
  }
}

// ---------------------------------------------------------------------------
// K3c: node attention  (unchanged)
// ---------------------------------------------------------------------------
__global__ __launch_bounds__(256) void k_node(
    const float* __restrict__ h,
    const float* __restrict__ ag, const float* __restrict__ ab,
    const float* __restrict__ am, const float* __restrict__ av,
    const float* __restrict__ attw, const float* __restrict__ nodew,
    const float* __restrict__ ng, const float* __restrict__ nb,
    const float* __restrict__ nm, const float* __restrict__ nv,
    float* __restrict__ dout)
{
  const int tid = threadIdx.x;
  __shared__ float ac[CC];
  __shared__ float tmp[CC];
  if (tid < CC) {
    float nc = 0.f;
    for (int o = 0; o < NCLS; ++o) nc = fmaf(nodew[o], attw[o * CC + tid], nc);
    const float s = ag[tid] * rsqrtf(av[tid] + EPS);
    const float off = ab[tid] - am[tid] * s;
    ac[tid] = nc * s;
    tmp[tid] = nc * off;
  }
  __syncthreads();
  if (tid == 0) {
    float b = 0.f;
    for (int c = 0; c < CC; ++c) b += tmp[c];
    tmp[0] = b;
  }
  __syncthreads();
  const float b0 = tmp[0];
  const size_t i = (size_t)blockIdx.x * 256 + tid;
  if (i < (size_t)NN * TV) {
    const int n = (int)(i / TV), f = (int)(i - (size_t)n * TV);
    const float* hb = h + (size_t)n * CC * TV + f;
    float xsum = b0;
    #pragma unroll 8
    for (int c = 0; c < CC; ++c) xsum = fmaf(hb[(size_t)c * TV], ac[c], xsum);
    const float s = ng[0] * rsqrtf(nv[0] + EPS);
    const float y = fmaf(xsum - nm[0], s, nb[0]);
    dout[NN * NCLS + i] = 1.f / (1.f + expf(-y));
  }
}

// ---------------------------------------------------------------------------
extern "C" void kernel_launch(void* const* d_in, const int* in_sizes, int n_in,
                              void* d_out, int out_size, void* d_ws, size_t ws_size,
                              hipStream_t stream) {
  const float* x        = (const float*)d_in[0];
  const float* A        = (const float*)d_in[1];
  const float* sgc_w    = (const float*)d_in[2];
  const float* sgc_b    = (const float*)d_in[3];
  const float* M        = (const float*)d_in[4];
  const float* bnA_g    = (const float*)d_in[5];
  const float* bnA_b    = (const float*)d_in[6];
  const float* bnA_m    = (const float*)d_in[7];
  const float* bnA_v    = (const float*)d_in[8];
  const float* tconv_w  = (const float*)d_in[9];
  const float* tconv_b  = (const float*)d_in[10];
  const float* bnB_g    = (const float*)d_in[11];
  const float* bnB_b    = (const float*)d_in[12];
  const float* bnB_m    = (const float*)d_in[13];
  const float* bnB_v    = (const float*)d_in[14];
  const float* fc_w     = (const float*)d_in[15];
  const float* fc_b     = (const float*)d_in[16];
  const float* attbn_g  = (const float*)d_in[17];
  const float* attbn_b  = (const float*)d_in[18];
  const float* attbn_m  = (const float*)d_in[19];
  const float* attbn_v  = (const float*)d_in[20];
  // d_in[21..34]: transformer branch params — dead code in the reference.
  const float* attconv_w  = (const float*)d_in[35];
  const float* nodeconv_w = (const float*)d_in[36];
  const float* nodebn_g   = (const float*)d_in[37];
  const float* nodebn_b   = (const float*)d_in[38];
  const float* nodebn_m   = (const float*)d_in[39];
  const float* nodebn_v   = (const float*)d_in[40];
  const float* edgeconv_w = (const float*)d_in[41];
  const float* edgebn_g   = (const float*)d_in[42];
  const float* edgebn_b   = (const float*)d_in[43];
  const float* edgebn_m   = (const float*)d_in[44];
  const float* edgebn_v   = (const float*)d_in[45];

  // workspace layout
  float* pooled = (float*)d_ws;                              // 1024 f32
  float* hmeanv = pooled + NN * CC;                          // 26624 f32
  unsigned short* W1all = (unsigned short*)(hmeanv + (size_t)NN * CC * VV);
  unsigned short* W2all = W1all + W1_ELEMS;
  unsigned short* AMall = W2all + W2_ELEMS;
  unsigned short* bufA  = AMall + AM_ELEMS;                  // bf16 hA
  unsigned short* bufBh = bufA + (size_t)NN * CC * TV;       // bf16 h (L0/L1)
  float* bufB = (float*)(bufBh + (size_t)NN * CC * TV);      // f32 h (L2)
  float* out = (float*)d_out;

  const int PREP_TOT = W1_ELEMS + W2_ELEMS + AM_ELEMS;
  k_prep_all<<<(PREP_TOT + 255) / 256, 256, 0, stream>>>(
      sgc_w, tconv_w, A, M, W1all, W2all, AMall);

  const int GF = NN * 159;           // fused grid
  const int NFC = (TV + 255) >> 8;   // 65
  for (int i = 0; i < 3; ++i) {
    const unsigned short* W1i = W1all + (size_t)i * OO * CC;
    const unsigned short* W2i = W2all + (size_t)i * CC * 576;
    const unsigned short* AMi = AMall + (size_t)i * KK * 1024;
    if (i == 0)
      k_fused_sgc<1><<<GF, 512, 0, stream>>>(
          x, W1i, sgc_b, AMi,
          bnA_g, bnA_b, bnA_m, bnA_v, bufA);
    else
      k_fused_sgc<0><<<GF, 512, 0, stream>>>(
          bufBh, W1i, sgc_b + i * OO, AMi,
          bnA_g + i * CC, bnA_b + i * CC, bnA_m + i * CC, bnA_v + i * CC,
          bufA);
    if (i < 2)
      k_tconv_mfma<0><<<NN * NFC, 512, 0, stream>>>(
          bufA, W2i, tconv_b + i * CC,
          bnB_g + i * CC, bnB_b + i * CC, bnB_m + i * CC, bnB_v + i * CC,
          (void*)bufBh);
    else
      k_tconv_mfma<1><<<NN * NFC, 512, 0, stream>>>(
          bufA, W2i, tconv_b + i * CC,
          bnB_g + i * CC, bnB_b + i * CC, bnB_m + i * CC, bnB_v + i * CC,
          (void*)bufB);
  }
  k_pool<<<NN * CC, 256, 0, stream>>>(bufB, pooled, hmeanv);
  k_head_edge<<<NN, 256, 0, stream>>>(pooled, hmeanv, fc_w, fc_b,
      attbn_g, attbn_b, attbn_m, attbn_v, attconv_w, edgeconv_w,
      edgebn_g, edgebn_b, edgebn_m, edgebn_v, out);
  k_node<<<((size_t)NN * TV + 255) / 256, 256, 0, stream>>>(
      bufB, attbn_g, attbn_b, attbn_m, attbn_v, attconv_w, nodeconv_w,
      nodebn_g, nodebn_b, nodebn_m, nodebn_v, out);
}